// Round 2
// baseline (413.134 us; speedup 1.0000x reference)
//
#include <hip/hip_runtime.h>
#include <cstdint>

#define N_SAMPLES 16384
#define DIM 2048
#define PDIM 256
#define NB 32
#define NL 100
#define NSEG (NB * NL)
#define CHUNK 64   // columns per segmean WG: LDS acc = 100*64*4 = 25.6 KB

typedef float floatx4 __attribute__((ext_vector_type(4)));
typedef __bf16 bf16x8 __attribute__((ext_vector_type(8)));

__device__ __forceinline__ unsigned short f32_to_bf16(float f) {
    unsigned int u = __float_as_uint(f);
    u += 0x7fffu + ((u >> 16) & 1u);   // round-to-nearest-even
    return (unsigned short)(u >> 16);
}

// ---------------------------------------------------------------------------
// prep: convert weights to bf16, combine biases, build seg index
// ---------------------------------------------------------------------------
__global__ __launch_bounds__(256) void prep_kernel(
    const float* __restrict__ W1w, const float* __restrict__ W1b,
    const float* __restrict__ W2w, const float* __restrict__ W2b,
    const int* __restrict__ label, const int* __restrict__ lbatch,
    unsigned short* __restrict__ W1bf, unsigned short* __restrict__ W2bf,
    float* __restrict__ bias, int* __restrict__ seg)
{
    int i = blockIdx.x * 256 + threadIdx.x;   // grid covers PDIM*DIM exactly
    W1bf[i] = f32_to_bf16(W1w[i]);
    W2bf[i] = f32_to_bf16(W2w[i]);
    if (i < PDIM) bias[i] = W1b[i] + W2b[i];
    if (i < N_SAMPLES) seg[i] = lbatch[i] * NL + label[i];
}

// ---------------------------------------------------------------------------
// segmean v2: WG = (batch b, 64-col chunk). 512 threads = 8 waves; wave w
// processes rows r0+w, r0+w+8, ... — lane = column (64 cols, 2 lanes/bank =
// free). LDS acc[label][col] via atomicAdd (cross-wave same-(l,c) collisions
// rare with random labels). 25.6 KB LDS -> 4 blocks/CU x 8 waves = 100% occ.
// Also emits x as bf16 in the same pass (x read exactly once).
// ---------------------------------------------------------------------------
__global__ __launch_bounds__(512) void segmean_kernel(
    const float* __restrict__ x, const int* __restrict__ label,
    const int* __restrict__ lbatch,
    unsigned short* __restrict__ xb, unsigned short* __restrict__ Mb)
{
    __shared__ float acc[NL][CHUNK];   // 25.6 KB
    __shared__ float tot[CHUNK];
    __shared__ int cnt[NL];
    const int tid = threadIdx.x;
    const int b = blockIdx.y;
    const int c0 = blockIdx.x * CHUNK;
    const int row_off = tid >> 6;      // wave id, 0..7
    const int c = tid & 63;            // lane = column within chunk

    for (int i = tid; i < NL * CHUNK; i += 512) ((float*)acc)[i] = 0.f;
    if (tid < NL) cnt[tid] = 0;

    // lower_bound(b), lower_bound(b+1) over sorted label_batch (uniform -> broadcast)
    int lo = 0, hi = N_SAMPLES;
    while (lo < hi) { int mid = (lo + hi) >> 1; if (lbatch[mid] < b) lo = mid + 1; else hi = mid; }
    const int r0 = lo;
    hi = N_SAMPLES;
    while (lo < hi) { int mid = (lo + hi) >> 1; if (lbatch[mid] < b + 1) lo = mid + 1; else hi = mid; }
    const int r1 = lo;

    __syncthreads();
    for (int r = r0 + tid; r < r1; r += 512) atomicAdd(&cnt[label[r]], 1);

    const float* xp = x + c0 + c;
    unsigned short* xbp = xb + c0 + c;
    #pragma unroll 8
    for (int r = r0 + row_off; r < r1; r += 8) {
        int l = label[r];                         // wave-uniform broadcast
        float v = xp[(size_t)r * DIM];            // wave reads 256B contiguous
        atomicAdd(&acc[l][c], v);                 // banks = c%32: 2-way, free
        xbp[(size_t)r * DIM] = f32_to_bf16(v);
    }
    __syncthreads();

    if (tid < CHUNK) {
        float t = 0.f;
        #pragma unroll
        for (int l = 0; l < NL; ++l) t += acc[l][tid];
        tot[tid] = t;
    }
    __syncthreads();

    const int cb = r1 - r0;
    for (int l = row_off; l < NL; l += 8) {       // wave w writes labels w, w+8, ...
        int dc = cb - cnt[l];
        float m = (dc > 0) ? (tot[c] - acc[l][c]) / (float)dc : 0.f;
        Mb[(size_t)(b * NL + l) * DIM + c0 + c] = f32_to_bf16(m);
    }
}

// ---------------------------------------------------------------------------
// GEMM: C[M,256] = A[M,K]_bf16 @ B[256,K]_bf16^T  (B rows = output cols)
// m97 structure: 2-barrier K-loop, global_load_lds width 16,
// mfma_f32_16x16x32_bf16. 4 waves in 2x2; wave subtile (BM/2)x(BN/2).
// FUSE epilogue: += bias[col] + add[seg[row]*256 + col]
// ---------------------------------------------------------------------------
template<int BM, int BN, bool FUSE>
__global__ __launch_bounds__(256) void gemm_bt_kernel(
    const unsigned short* __restrict__ A,
    const unsigned short* __restrict__ B,
    float* __restrict__ C,
    const float* __restrict__ bias,
    const float* __restrict__ add,
    const int* __restrict__ seg,
    int K)
{
    constexpr int HBM = BM / 2, HBN = BN / 2;
    constexpr int FM = BM / 32, FN = BN / 32;
    __shared__ __align__(16) unsigned short ldsA[BM * 32];
    __shared__ __align__(16) unsigned short ldsB[BN * 32];
    const int tid = threadIdx.x;
    const int lane = tid & 63;
    const int wave = tid >> 6;
    const int wr = wave >> 1, wc = wave & 1;
    const int quad = lane >> 4, l15 = lane & 15;
    const int m0 = blockIdx.x * BM;
    const int n0 = blockIdx.y * BN;
    const int srow = lane >> 2, schunk = lane & 3;   // staging: 16 rows x 4 chunks of 8 bf16

    floatx4 acc[FM][FN];
    #pragma unroll
    for (int i = 0; i < FM; ++i)
        #pragma unroll
        for (int j = 0; j < FN; ++j) acc[i][j] = (floatx4){0.f, 0.f, 0.f, 0.f};

    const unsigned short* Abase = A + (size_t)(m0 + srow) * K + schunk * 8;
    const unsigned short* Bbase = B + (size_t)(n0 + srow) * K + schunk * 8;

    for (int kk = 0; kk < K; kk += 32) {
        __syncthreads();
        #pragma unroll
        for (int ii = 0; ii < BM / 64; ++ii) {   // wave w stages 16-row chunk (ii*4+w)
            const int ch = ii * 4 + wave;
            __builtin_amdgcn_global_load_lds(
                (const __attribute__((address_space(1))) void*)(Abase + (size_t)ch * 16 * K + kk),
                (__attribute__((address_space(3))) void*)&ldsA[ch * 16 * 32], 16, 0, 0);
        }
        #pragma unroll
        for (int ii = 0; ii < BN / 64; ++ii) {
            const int ch = ii * 4 + wave;
            __builtin_amdgcn_global_load_lds(
                (const __attribute__((address_space(1))) void*)(Bbase + (size_t)ch * 16 * K + kk),
                (__attribute__((address_space(3))) void*)&ldsB[ch * 16 * 32], 16, 0, 0);
        }
        __syncthreads();

        bf16x8 af[FM], bfr[FN];
        #pragma unroll
        for (int mi = 0; mi < FM; ++mi)
            af[mi] = *(const bf16x8*)&ldsA[(wr * HBM + mi * 16 + l15) * 32 + quad * 8];
        #pragma unroll
        for (int ni = 0; ni < FN; ++ni)
            bfr[ni] = *(const bf16x8*)&ldsB[(wc * HBN + ni * 16 + l15) * 32 + quad * 8];
        #pragma unroll
        for (int mi = 0; mi < FM; ++mi)
            #pragma unroll
            for (int ni = 0; ni < FN; ++ni)
                acc[mi][ni] = __builtin_amdgcn_mfma_f32_16x16x32_bf16(
                    af[mi], bfr[ni], acc[mi][ni], 0, 0, 0);
    }

    #pragma unroll
    for (int mi = 0; mi < FM; ++mi) {
        const int rbase = m0 + wr * HBM + mi * 16 + quad * 4;
        #pragma unroll
        for (int ni = 0; ni < FN; ++ni) {
            const int col = n0 + wc * HBN + ni * 16 + l15;
            float bsum = 0.f;
            if constexpr (FUSE) bsum = bias[col];
            #pragma unroll
            for (int r = 0; r < 4; ++r) {
                const int row = rbase + r;
                float v = acc[mi][ni][r];
                if constexpr (FUSE) v += bsum + add[(size_t)seg[row] * PDIM + col];
                C[(size_t)row * PDIM + col] = v;
            }
        }
    }
}

// ---------------------------------------------------------------------------
extern "C" void kernel_launch(void* const* d_in, const int* in_sizes, int n_in,
                              void* d_out, int out_size, void* d_ws, size_t ws_size,
                              hipStream_t stream)
{
    const float* x      = (const float*)d_in[0];
    const int*   label  = (const int*)d_in[1];
    const int*   lbatch = (const int*)d_in[2];
    const float* W1w    = (const float*)d_in[3];
    const float* W1b    = (const float*)d_in[4];
    const float* W2w    = (const float*)d_in[5];
    const float* W2b    = (const float*)d_in[6];
    float* out = (float*)d_out;

    char* ws = (char*)d_ws;
    size_t off = 0;
    auto alloc = [&](size_t bytes) {
        void* p = ws + off;
        off = (off + bytes + 255) & ~(size_t)255;
        return p;
    };
    unsigned short* xb   = (unsigned short*)alloc((size_t)N_SAMPLES * DIM * 2); // 67 MB
    unsigned short* Mb   = (unsigned short*)alloc((size_t)NSEG * DIM * 2);      // 13 MB
    unsigned short* W1bf = (unsigned short*)alloc((size_t)PDIM * DIM * 2);      // 1 MB
    unsigned short* W2bf = (unsigned short*)alloc((size_t)PDIM * DIM * 2);      // 1 MB
    float* MW2  = (float*)alloc((size_t)NSEG * PDIM * 4);                       // 3.3 MB
    float* bias = (float*)alloc(PDIM * 4);
    int*   seg  = (int*)alloc(N_SAMPLES * 4);

    prep_kernel<<<PDIM * DIM / 256, 256, 0, stream>>>(
        W1w, W1b, W2w, W2b, label, lbatch, W1bf, W2bf, bias, seg);

    segmean_kernel<<<dim3(DIM / CHUNK, NB), 512, 0, stream>>>(x, label, lbatch, xb, Mb);

    // MW2[3200,256] = M @ W2^T
    gemm_bt_kernel<64, 64, false><<<dim3(NSEG / 64, PDIM / 64), 256, 0, stream>>>(
        Mb, W2bf, MW2, nullptr, nullptr, nullptr, DIM);

    // out[16384,256] = x @ W1^T + bias + MW2[seg]
    gemm_bt_kernel<64, 128, true><<<dim3(N_SAMPLES / 64, PDIM / 128), 256, 0, stream>>>(
        xb, W1bf, out, bias, MW2, seg, DIM);
}

// Round 3
// 366.318 us; speedup vs baseline: 1.1278x; 1.1278x over previous
//
#include <hip/hip_runtime.h>
#include <cstdint>

#define N_SAMPLES 16384
#define DIM 2048
#define PDIM 256
#define NB 32
#define NL 100
#define NSEG (NB * NL)

typedef float floatx4 __attribute__((ext_vector_type(4)));
typedef __bf16 bf16x8 __attribute__((ext_vector_type(8)));

__device__ __forceinline__ unsigned short f32_to_bf16(float f) {
    unsigned int u = __float_as_uint(f);
    u += 0x7fffu + ((u >> 16) & 1u);   // round-to-nearest-even
    return (unsigned short)(u >> 16);
}

// ---------------------------------------------------------------------------
// prep: weights -> bf16, bias sum, seg index, zero hist + sum_b
// ---------------------------------------------------------------------------
__global__ __launch_bounds__(256) void prep_kernel(
    const float* __restrict__ W1w, const float* __restrict__ W1b,
    const float* __restrict__ W2w, const float* __restrict__ W2b,
    const int* __restrict__ label, const int* __restrict__ lbatch,
    unsigned short* __restrict__ W1bf, unsigned short* __restrict__ W2bf,
    float* __restrict__ bias, int* __restrict__ seg,
    int* __restrict__ hist, float* __restrict__ sum_b)
{
    int i = blockIdx.x * 256 + threadIdx.x;   // grid = PDIM*DIM threads
    W1bf[i] = f32_to_bf16(W1w[i]);
    W2bf[i] = f32_to_bf16(W2w[i]);
    if (i < PDIM) bias[i] = W1b[i] + W2b[i];
    if (i < N_SAMPLES) seg[i] = lbatch[i] * NL + label[i];
    if (i < NSEG) hist[i] = 0;
    if (i < NB * DIM) sum_b[i] = 0.f;
}

__global__ __launch_bounds__(256) void hist_kernel(
    const int* __restrict__ seg, int* __restrict__ hist)
{
    int i = blockIdx.x * 256 + threadIdx.x;
    atomicAdd(&hist[seg[i]], 1);
}

// ---------------------------------------------------------------------------
// scan: single WG exclusive prefix over hist[3200] -> offs[3201], cursor copy
// ---------------------------------------------------------------------------
#define SCAN_BPT 13   // 256*13 = 3328 >= 3200
__global__ __launch_bounds__(256) void scan_kernel(
    const int* __restrict__ hist, int* __restrict__ offs, int* __restrict__ cursor)
{
    __shared__ int ps[256];
    const int t = threadIdx.x;
    int local = 0;
    #pragma unroll
    for (int k = 0; k < SCAN_BPT; ++k) {
        int bin = t * SCAN_BPT + k;
        if (bin < NSEG) local += hist[bin];
    }
    ps[t] = local;
    __syncthreads();
    for (int d = 1; d < 256; d <<= 1) {
        int v = (t >= d) ? ps[t - d] : 0;
        __syncthreads();
        ps[t] += v;
        __syncthreads();
    }
    int run = ps[t] - local;   // exclusive start for this thread's range
    #pragma unroll
    for (int k = 0; k < SCAN_BPT; ++k) {
        int bin = t * SCAN_BPT + k;
        if (bin < NSEG) {
            offs[bin] = run;
            cursor[bin] = run;
            run += hist[bin];
        }
    }
    if (t == 255) offs[NSEG] = ps[255];   // = N_SAMPLES
}

__global__ __launch_bounds__(256) void scatter_kernel(
    const int* __restrict__ seg, int* __restrict__ cursor, int* __restrict__ perm)
{
    int i = blockIdx.x * 256 + threadIdx.x;
    int pos = atomicAdd(&cursor[seg[i]], 1);
    perm[pos] = i;
}

// ---------------------------------------------------------------------------
// segsum: wave = (segment, 64-col chunk). Register accumulation over the
// segment's ~5 rows (gathered via perm); also emits x as bf16 (each row/col
// touched exactly once across the grid). Batch sum via one 64-lane global
// atomicAdd per wave. No LDS, no serial batch scan.
// ---------------------------------------------------------------------------
__global__ __launch_bounds__(256) void segsum_kernel(
    const float* __restrict__ x, const int* __restrict__ perm,
    const int* __restrict__ offs,
    unsigned short* __restrict__ xb, float* __restrict__ sum_bl,
    float* __restrict__ sum_b)
{
    const int tid = threadIdx.x;
    const int w = tid >> 6, lane = tid & 63;
    const int s = blockIdx.y * 4 + w;          // segment, 0..3199
    const int c = blockIdx.x * 64 + lane;      // column
    const int beg = offs[s], end = offs[s + 1];

    float sum = 0.f;
    for (int base = beg; base < end; base += 64) {
        int p = (base + lane < end) ? perm[base + lane] : 0;
        const int n = min(end - base, 64);
        #pragma unroll 4
        for (int j = 0; j < n; ++j) {
            int r = __shfl(p, j);                       // row index, wave-uniform
            float v = x[(size_t)r * DIM + c];           // 256B coalesced per wave
            sum += v;
            xb[(size_t)r * DIM + c] = f32_to_bf16(v);   // 128B coalesced store
        }
    }
    sum_bl[(size_t)s * DIM + c] = sum;
    atomicAdd(&sum_b[(s / NL) * DIM + c], sum);
}

// ---------------------------------------------------------------------------
// meanm: fully parallel LOO mean -> Mb bf16. thread = (segment, 4 cols)
// ---------------------------------------------------------------------------
__global__ __launch_bounds__(256) void meanm_kernel(
    const float* __restrict__ sum_bl, const float* __restrict__ sum_b,
    const int* __restrict__ hist, const int* __restrict__ offs,
    unsigned short* __restrict__ Mb)
{
    int idx = blockIdx.x * 256 + threadIdx.x;  // NSEG * 512 total
    int s = idx >> 9;
    int c = (idx & 511) * 4;
    int b = s / NL;
    int cntb = offs[(b + 1) * NL] - offs[b * NL];
    int dc = cntb - hist[s];
    float inv = (dc > 0) ? 1.f / (float)dc : 0.f;
    floatx4 sl = *(const floatx4*)&sum_bl[(size_t)s * DIM + c];
    floatx4 sb = *(const floatx4*)&sum_b[b * DIM + c];
    ushort4 o;
    o.x = f32_to_bf16((sb[0] - sl[0]) * inv);
    o.y = f32_to_bf16((sb[1] - sl[1]) * inv);
    o.z = f32_to_bf16((sb[2] - sl[2]) * inv);
    o.w = f32_to_bf16((sb[3] - sl[3]) * inv);
    *(ushort4*)&Mb[(size_t)s * DIM + c] = o;
}

// ---------------------------------------------------------------------------
// GEMM: C[M,256] = A[M,K]_bf16 @ B[256,K]_bf16^T  (m97 structure, unchanged)
// FUSE epilogue: += bias[col] + add[seg[row]*256 + col]
// ---------------------------------------------------------------------------
template<int BM, int BN, bool FUSE>
__global__ __launch_bounds__(256) void gemm_bt_kernel(
    const unsigned short* __restrict__ A,
    const unsigned short* __restrict__ B,
    float* __restrict__ C,
    const float* __restrict__ bias,
    const float* __restrict__ add,
    const int* __restrict__ seg,
    int K)
{
    constexpr int HBM = BM / 2, HBN = BN / 2;
    constexpr int FM = BM / 32, FN = BN / 32;
    __shared__ __align__(16) unsigned short ldsA[BM * 32];
    __shared__ __align__(16) unsigned short ldsB[BN * 32];
    const int tid = threadIdx.x;
    const int lane = tid & 63;
    const int wave = tid >> 6;
    const int wr = wave >> 1, wc = wave & 1;
    const int quad = lane >> 4, l15 = lane & 15;
    const int m0 = blockIdx.x * BM;
    const int n0 = blockIdx.y * BN;
    const int srow = lane >> 2, schunk = lane & 3;

    floatx4 acc[FM][FN];
    #pragma unroll
    for (int i = 0; i < FM; ++i)
        #pragma unroll
        for (int j = 0; j < FN; ++j) acc[i][j] = (floatx4){0.f, 0.f, 0.f, 0.f};

    const unsigned short* Abase = A + (size_t)(m0 + srow) * K + schunk * 8;
    const unsigned short* Bbase = B + (size_t)(n0 + srow) * K + schunk * 8;

    for (int kk = 0; kk < K; kk += 32) {
        __syncthreads();
        #pragma unroll
        for (int ii = 0; ii < BM / 64; ++ii) {
            const int ch = ii * 4 + wave;
            __builtin_amdgcn_global_load_lds(
                (const __attribute__((address_space(1))) void*)(Abase + (size_t)ch * 16 * K + kk),
                (__attribute__((address_space(3))) void*)&ldsA[ch * 16 * 32], 16, 0, 0);
        }
        #pragma unroll
        for (int ii = 0; ii < BN / 64; ++ii) {
            const int ch = ii * 4 + wave;
            __builtin_amdgcn_global_load_lds(
                (const __attribute__((address_space(1))) void*)(Bbase + (size_t)ch * 16 * K + kk),
                (__attribute__((address_space(3))) void*)&ldsB[ch * 16 * 32], 16, 0, 0);
        }
        __syncthreads();

        bf16x8 af[FM], bfr[FN];
        #pragma unroll
        for (int mi = 0; mi < FM; ++mi)
            af[mi] = *(const bf16x8*)&ldsA[(wr * HBM + mi * 16 + l15) * 32 + quad * 8];
        #pragma unroll
        for (int ni = 0; ni < FN; ++ni)
            bfr[ni] = *(const bf16x8*)&ldsB[(wc * HBN + ni * 16 + l15) * 32 + quad * 8];
        #pragma unroll
        for (int mi = 0; mi < FM; ++mi)
            #pragma unroll
            for (int ni = 0; ni < FN; ++ni)
                acc[mi][ni] = __builtin_amdgcn_mfma_f32_16x16x32_bf16(
                    af[mi], bfr[ni], acc[mi][ni], 0, 0, 0);
    }

    #pragma unroll
    for (int mi = 0; mi < FM; ++mi) {
        const int rbase = m0 + wr * HBM + mi * 16 + quad * 4;
        #pragma unroll
        for (int ni = 0; ni < FN; ++ni) {
            const int col = n0 + wc * HBN + ni * 16 + l15;
            float bsum = 0.f;
            if constexpr (FUSE) bsum = bias[col];
            #pragma unroll
            for (int r = 0; r < 4; ++r) {
                const int row = rbase + r;
                float v = acc[mi][ni][r];
                if constexpr (FUSE) v += bsum + add[(size_t)seg[row] * PDIM + col];
                C[(size_t)row * PDIM + col] = v;
            }
        }
    }
}

// ---------------------------------------------------------------------------
extern "C" void kernel_launch(void* const* d_in, const int* in_sizes, int n_in,
                              void* d_out, int out_size, void* d_ws, size_t ws_size,
                              hipStream_t stream)
{
    const float* x      = (const float*)d_in[0];
    const int*   label  = (const int*)d_in[1];
    const int*   lbatch = (const int*)d_in[2];
    const float* W1w    = (const float*)d_in[3];
    const float* W1b    = (const float*)d_in[4];
    const float* W2w    = (const float*)d_in[5];
    const float* W2b    = (const float*)d_in[6];
    float* out = (float*)d_out;

    char* ws = (char*)d_ws;
    size_t off = 0;
    auto alloc = [&](size_t bytes) {
        void* p = ws + off;
        off = (off + bytes + 255) & ~(size_t)255;
        return p;
    };
    unsigned short* xb   = (unsigned short*)alloc((size_t)N_SAMPLES * DIM * 2); // 67 MB
    unsigned short* Mb   = (unsigned short*)alloc((size_t)NSEG * DIM * 2);      // 13 MB
    unsigned short* W1bf = (unsigned short*)alloc((size_t)PDIM * DIM * 2);
    unsigned short* W2bf = (unsigned short*)alloc((size_t)PDIM * DIM * 2);
    float* MW2    = (float*)alloc((size_t)NSEG * PDIM * 4);                     // 3.3 MB
    float* sum_bl = (float*)alloc((size_t)NSEG * DIM * 4);                      // 26 MB
    float* sum_b  = (float*)alloc((size_t)NB * DIM * 4);
    float* bias   = (float*)alloc(PDIM * 4);
    int*   seg    = (int*)alloc(N_SAMPLES * 4);
    int*   perm   = (int*)alloc(N_SAMPLES * 4);
    int*   hist   = (int*)alloc(NSEG * 4);
    int*   offs   = (int*)alloc((NSEG + 1) * 4);
    int*   cursor = (int*)alloc(NSEG * 4);

    prep_kernel<<<PDIM * DIM / 256, 256, 0, stream>>>(
        W1w, W1b, W2w, W2b, label, lbatch, W1bf, W2bf, bias, seg, hist, sum_b);

    hist_kernel<<<N_SAMPLES / 256, 256, 0, stream>>>(seg, hist);
    scan_kernel<<<1, 256, 0, stream>>>(hist, offs, cursor);
    scatter_kernel<<<N_SAMPLES / 256, 256, 0, stream>>>(seg, cursor, perm);

    segsum_kernel<<<dim3(DIM / 64, NSEG / 4), 256, 0, stream>>>(
        x, perm, offs, xb, sum_bl, sum_b);

    meanm_kernel<<<NSEG * 512 / 256, 256, 0, stream>>>(sum_bl, sum_b, hist, offs, Mb);

    // MW2[3200,256] = M @ W2^T
    gemm_bt_kernel<64, 64, false><<<dim3(NSEG / 64, PDIM / 64), 256, 0, stream>>>(
        Mb, W2bf, MW2, nullptr, nullptr, nullptr, DIM);

    // out[16384,256] = x @ W1^T + bias + MW2[seg]
    gemm_bt_kernel<64, 128, true><<<dim3(N_SAMPLES / 64, PDIM / 128), 256, 0, stream>>>(
        xb, W1bf, out, bias, MW2, seg, DIM);
}

// Round 4
// 323.969 us; speedup vs baseline: 1.2752x; 1.1307x over previous
//
#include <hip/hip_runtime.h>
#include <cstdint>

#define N_SAMPLES 16384
#define DIM 2048
#define PDIM 256
#define NB 32
#define NL 100
#define NSEG (NB * NL)

typedef float floatx4 __attribute__((ext_vector_type(4)));
typedef __bf16 bf16x8 __attribute__((ext_vector_type(8)));

__device__ __forceinline__ unsigned short f32_to_bf16(float f) {
    unsigned int u = __float_as_uint(f);
    u += 0x7fffu + ((u >> 16) & 1u);   // round-to-nearest-even
    return (unsigned short)(u >> 16);
}

// ---------------------------------------------------------------------------
// prep: weights -> bf16, bias sum, seg index, zero hist
// ---------------------------------------------------------------------------
__global__ __launch_bounds__(256) void prep_kernel(
    const float* __restrict__ W1w, const float* __restrict__ W1b,
    const float* __restrict__ W2w, const float* __restrict__ W2b,
    const int* __restrict__ label, const int* __restrict__ lbatch,
    unsigned short* __restrict__ W1bf, unsigned short* __restrict__ W2bf,
    float* __restrict__ bias, int* __restrict__ seg,
    int* __restrict__ hist)
{
    int i = blockIdx.x * 256 + threadIdx.x;   // grid = PDIM*DIM threads
    W1bf[i] = f32_to_bf16(W1w[i]);
    W2bf[i] = f32_to_bf16(W2w[i]);
    if (i < PDIM) bias[i] = W1b[i] + W2b[i];
    if (i < N_SAMPLES) seg[i] = lbatch[i] * NL + label[i];
    if (i < NSEG) hist[i] = 0;
}

__global__ __launch_bounds__(256) void hist_kernel(
    const int* __restrict__ seg, int* __restrict__ hist)
{
    int i = blockIdx.x * 256 + threadIdx.x;
    atomicAdd(&hist[seg[i]], 1);
}

// ---------------------------------------------------------------------------
// scan: single WG exclusive prefix over hist[3200] -> offs[3201], cursor copy
// ---------------------------------------------------------------------------
#define SCAN_BPT 13   // 256*13 = 3328 >= 3200
__global__ __launch_bounds__(256) void scan_kernel(
    const int* __restrict__ hist, int* __restrict__ offs, int* __restrict__ cursor)
{
    __shared__ int ps[256];
    const int t = threadIdx.x;
    int local = 0;
    #pragma unroll
    for (int k = 0; k < SCAN_BPT; ++k) {
        int bin = t * SCAN_BPT + k;
        if (bin < NSEG) local += hist[bin];
    }
    ps[t] = local;
    __syncthreads();
    for (int d = 1; d < 256; d <<= 1) {
        int v = (t >= d) ? ps[t - d] : 0;
        __syncthreads();
        ps[t] += v;
        __syncthreads();
    }
    int run = ps[t] - local;   // exclusive start for this thread's range
    #pragma unroll
    for (int k = 0; k < SCAN_BPT; ++k) {
        int bin = t * SCAN_BPT + k;
        if (bin < NSEG) {
            offs[bin] = run;
            cursor[bin] = run;
            run += hist[bin];
        }
    }
    if (t == 255) offs[NSEG] = ps[255];   // = N_SAMPLES
}

__global__ __launch_bounds__(256) void scatter_kernel(
    const int* __restrict__ seg, int* __restrict__ cursor, int* __restrict__ perm)
{
    int i = blockIdx.x * 256 + threadIdx.x;
    int pos = atomicAdd(&cursor[seg[i]], 1);
    perm[pos] = i;
}

// ---------------------------------------------------------------------------
// segsum v3: wave = (segment, 256-col chunk), lane = float4 (1KB/wave-load).
// Register accumulation over the segment's ~5 rows (via perm); emits x as
// bf16 in the same pass. No LDS, no atomics, 4x fewer VMEM insts than v2.
// ---------------------------------------------------------------------------
__global__ __launch_bounds__(256) void segsum_kernel(
    const float* __restrict__ x, const int* __restrict__ perm,
    const int* __restrict__ offs,
    unsigned short* __restrict__ xb, float* __restrict__ sum_bl)
{
    const int tid = threadIdx.x;
    const int w = tid >> 6, lane = tid & 63;
    const int s = blockIdx.y * 4 + w;              // segment, 0..3199
    const int c = blockIdx.x * 256 + lane * 4;     // column (float4 per lane)
    const int beg = offs[s], end = offs[s + 1];

    floatx4 sum = {0.f, 0.f, 0.f, 0.f};
    for (int base = beg; base < end; base += 64) {
        int p = (base + lane < end) ? perm[base + lane] : 0;
        const int n = min(end - base, 64);
        #pragma unroll 4
        for (int j = 0; j < n; ++j) {
            int r = __shfl(p, j);                              // wave-uniform row
            floatx4 v = *(const floatx4*)&x[(size_t)r * DIM + c]; // 1KB/wave
            sum += v;
            ushort4 o;
            o.x = f32_to_bf16(v[0]); o.y = f32_to_bf16(v[1]);
            o.z = f32_to_bf16(v[2]); o.w = f32_to_bf16(v[3]);
            *(ushort4*)&xb[(size_t)r * DIM + c] = o;           // 512B/wave
        }
    }
    *(floatx4*)&sum_bl[(size_t)s * DIM + c] = sum;
}

// ---------------------------------------------------------------------------
// sumb: sum_b[b][:] = sum over 100 labels of sum_bl[b*NL+l][:]
// thread = (batch, float4 col). 26 MB read, fully coalesced.
// ---------------------------------------------------------------------------
__global__ __launch_bounds__(256) void sumb_kernel(
    const float* __restrict__ sum_bl, float* __restrict__ sum_b)
{
    int idx = blockIdx.x * 256 + threadIdx.x;   // NB * DIM/4 total
    int b = idx / (DIM / 4);
    int c = (idx % (DIM / 4)) * 4;
    floatx4 t = {0.f, 0.f, 0.f, 0.f};
    #pragma unroll 4
    for (int l = 0; l < NL; ++l)
        t += *(const floatx4*)&sum_bl[(size_t)(b * NL + l) * DIM + c];
    *(floatx4*)&sum_b[(size_t)b * DIM + c] = t;
}

// ---------------------------------------------------------------------------
// meanm: fully parallel LOO mean -> Mb bf16. thread = (segment, 4 cols)
// ---------------------------------------------------------------------------
__global__ __launch_bounds__(256) void meanm_kernel(
    const float* __restrict__ sum_bl, const float* __restrict__ sum_b,
    const int* __restrict__ hist, const int* __restrict__ offs,
    unsigned short* __restrict__ Mb)
{
    int idx = blockIdx.x * 256 + threadIdx.x;  // NSEG * 512 total
    int s = idx >> 9;
    int c = (idx & 511) * 4;
    int b = s / NL;
    int cntb = offs[(b + 1) * NL] - offs[b * NL];
    int dc = cntb - hist[s];
    float inv = (dc > 0) ? 1.f / (float)dc : 0.f;
    floatx4 sl = *(const floatx4*)&sum_bl[(size_t)s * DIM + c];
    floatx4 sb = *(const floatx4*)&sum_b[(size_t)b * DIM + c];
    ushort4 o;
    o.x = f32_to_bf16((sb[0] - sl[0]) * inv);
    o.y = f32_to_bf16((sb[1] - sl[1]) * inv);
    o.z = f32_to_bf16((sb[2] - sl[2]) * inv);
    o.w = f32_to_bf16((sb[3] - sl[3]) * inv);
    *(ushort4*)&Mb[(size_t)s * DIM + c] = o;
}

// ---------------------------------------------------------------------------
// GEMM: C[M,256] = A[M,K]_bf16 @ B[256,K]_bf16^T  (m97 structure)
// FUSE epilogue: += bias[col] + add[seg[row]*256 + col]
// ---------------------------------------------------------------------------
template<int BM, int BN, bool FUSE>
__global__ __launch_bounds__(256) void gemm_bt_kernel(
    const unsigned short* __restrict__ A,
    const unsigned short* __restrict__ B,
    float* __restrict__ C,
    const float* __restrict__ bias,
    const float* __restrict__ add,
    const int* __restrict__ seg,
    int K)
{
    constexpr int HBM = BM / 2, HBN = BN / 2;
    constexpr int FM = BM / 32, FN = BN / 32;
    __shared__ __align__(16) unsigned short ldsA[BM * 32];
    __shared__ __align__(16) unsigned short ldsB[BN * 32];
    const int tid = threadIdx.x;
    const int lane = tid & 63;
    const int wave = tid >> 6;
    const int wr = wave >> 1, wc = wave & 1;
    const int quad = lane >> 4, l15 = lane & 15;
    const int m0 = blockIdx.x * BM;
    const int n0 = blockIdx.y * BN;
    const int srow = lane >> 2, schunk = lane & 3;

    floatx4 acc[FM][FN];
    #pragma unroll
    for (int i = 0; i < FM; ++i)
        #pragma unroll
        for (int j = 0; j < FN; ++j) acc[i][j] = (floatx4){0.f, 0.f, 0.f, 0.f};

    const unsigned short* Abase = A + (size_t)(m0 + srow) * K + schunk * 8;
    const unsigned short* Bbase = B + (size_t)(n0 + srow) * K + schunk * 8;

    for (int kk = 0; kk < K; kk += 32) {
        __syncthreads();
        #pragma unroll
        for (int ii = 0; ii < BM / 64; ++ii) {
            const int ch = ii * 4 + wave;
            __builtin_amdgcn_global_load_lds(
                (const __attribute__((address_space(1))) void*)(Abase + (size_t)ch * 16 * K + kk),
                (__attribute__((address_space(3))) void*)&ldsA[ch * 16 * 32], 16, 0, 0);
        }
        #pragma unroll
        for (int ii = 0; ii < BN / 64; ++ii) {
            const int ch = ii * 4 + wave;
            __builtin_amdgcn_global_load_lds(
                (const __attribute__((address_space(1))) void*)(Bbase + (size_t)ch * 16 * K + kk),
                (__attribute__((address_space(3))) void*)&ldsB[ch * 16 * 32], 16, 0, 0);
        }
        __syncthreads();

        bf16x8 af[FM], bfr[FN];
        #pragma unroll
        for (int mi = 0; mi < FM; ++mi)
            af[mi] = *(const bf16x8*)&ldsA[(wr * HBM + mi * 16 + l15) * 32 + quad * 8];
        #pragma unroll
        for (int ni = 0; ni < FN; ++ni)
            bfr[ni] = *(const bf16x8*)&ldsB[(wc * HBN + ni * 16 + l15) * 32 + quad * 8];
        #pragma unroll
        for (int mi = 0; mi < FM; ++mi)
            #pragma unroll
            for (int ni = 0; ni < FN; ++ni)
                acc[mi][ni] = __builtin_amdgcn_mfma_f32_16x16x32_bf16(
                    af[mi], bfr[ni], acc[mi][ni], 0, 0, 0);
    }

    #pragma unroll
    for (int mi = 0; mi < FM; ++mi) {
        const int rbase = m0 + wr * HBM + mi * 16 + quad * 4;
        #pragma unroll
        for (int ni = 0; ni < FN; ++ni) {
            const int col = n0 + wc * HBN + ni * 16 + l15;
            float bsum = 0.f;
            if constexpr (FUSE) bsum = bias[col];
            #pragma unroll
            for (int r = 0; r < 4; ++r) {
                const int row = rbase + r;
                float v = acc[mi][ni][r];
                if constexpr (FUSE) v += bsum + add[(size_t)seg[row] * PDIM + col];
                C[(size_t)row * PDIM + col] = v;
            }
        }
    }
}

// ---------------------------------------------------------------------------
extern "C" void kernel_launch(void* const* d_in, const int* in_sizes, int n_in,
                              void* d_out, int out_size, void* d_ws, size_t ws_size,
                              hipStream_t stream)
{
    const float* x      = (const float*)d_in[0];
    const int*   label  = (const int*)d_in[1];
    const int*   lbatch = (const int*)d_in[2];
    const float* W1w    = (const float*)d_in[3];
    const float* W1b    = (const float*)d_in[4];
    const float* W2w    = (const float*)d_in[5];
    const float* W2b    = (const float*)d_in[6];
    float* out = (float*)d_out;

    char* ws = (char*)d_ws;
    size_t off = 0;
    auto alloc = [&](size_t bytes) {
        void* p = ws + off;
        off = (off + bytes + 255) & ~(size_t)255;
        return p;
    };
    unsigned short* xb   = (unsigned short*)alloc((size_t)N_SAMPLES * DIM * 2); // 67 MB
    unsigned short* Mb   = (unsigned short*)alloc((size_t)NSEG * DIM * 2);      // 13 MB
    unsigned short* W1bf = (unsigned short*)alloc((size_t)PDIM * DIM * 2);
    unsigned short* W2bf = (unsigned short*)alloc((size_t)PDIM * DIM * 2);
    float* MW2    = (float*)alloc((size_t)NSEG * PDIM * 4);                     // 3.3 MB
    float* sum_bl = (float*)alloc((size_t)NSEG * DIM * 4);                      // 26 MB
    float* sum_b  = (float*)alloc((size_t)NB * DIM * 4);
    float* bias   = (float*)alloc(PDIM * 4);
    int*   seg    = (int*)alloc(N_SAMPLES * 4);
    int*   perm   = (int*)alloc(N_SAMPLES * 4);
    int*   hist   = (int*)alloc(NSEG * 4);
    int*   offs   = (int*)alloc((NSEG + 1) * 4);
    int*   cursor = (int*)alloc(NSEG * 4);

    prep_kernel<<<PDIM * DIM / 256, 256, 0, stream>>>(
        W1w, W1b, W2w, W2b, label, lbatch, W1bf, W2bf, bias, seg, hist);

    hist_kernel<<<N_SAMPLES / 256, 256, 0, stream>>>(seg, hist);
    scan_kernel<<<1, 256, 0, stream>>>(hist, offs, cursor);
    scatter_kernel<<<N_SAMPLES / 256, 256, 0, stream>>>(seg, cursor, perm);

    segsum_kernel<<<dim3(DIM / 256, NSEG / 4), 256, 0, stream>>>(
        x, perm, offs, xb, sum_bl);

    sumb_kernel<<<NB * (DIM / 4) / 256, 256, 0, stream>>>(sum_bl, sum_b);

    meanm_kernel<<<NSEG * 512 / 256, 256, 0, stream>>>(sum_bl, sum_b, hist, offs, Mb);

    // MW2[3200,256] = M @ W2^T
    gemm_bt_kernel<64, 64, false><<<dim3(NSEG / 64, PDIM / 64), 256, 0, stream>>>(
        Mb, W2bf, MW2, nullptr, nullptr, nullptr, DIM);

    // out[16384,256] = x @ W1^T + bias + MW2[seg]
    gemm_bt_kernel<64, 128, true><<<dim3(N_SAMPLES / 64, PDIM / 128), 256, 0, stream>>>(
        xb, W1bf, out, bias, MW2, seg, DIM);
}

// Round 5
// 322.082 us; speedup vs baseline: 1.2827x; 1.0059x over previous
//
#include <hip/hip_runtime.h>
#include <cstdint>

#define N_SAMPLES 16384
#define DIM 2048
#define PDIM 256
#define NB 32
#define NL 100
#define NSEG (NB * NL)

typedef float floatx4 __attribute__((ext_vector_type(4)));
typedef __bf16 bf16x8 __attribute__((ext_vector_type(8)));

__device__ __forceinline__ unsigned short f32_to_bf16(float f) {
    unsigned int u = __float_as_uint(f);
    u += 0x7fffu + ((u >> 16) & 1u);   // round-to-nearest-even
    return (unsigned short)(u >> 16);
}

// ---------------------------------------------------------------------------
// prep: weights -> bf16, bias sum, seg index, zero hist
// ---------------------------------------------------------------------------
__global__ __launch_bounds__(256) void prep_kernel(
    const float* __restrict__ W1w, const float* __restrict__ W1b,
    const float* __restrict__ W2w, const float* __restrict__ W2b,
    const int* __restrict__ label, const int* __restrict__ lbatch,
    unsigned short* __restrict__ W1bf, unsigned short* __restrict__ W2bf,
    float* __restrict__ bias, int* __restrict__ seg,
    int* __restrict__ hist)
{
    int i = blockIdx.x * 256 + threadIdx.x;   // grid = PDIM*DIM threads
    W1bf[i] = f32_to_bf16(W1w[i]);
    W2bf[i] = f32_to_bf16(W2w[i]);
    if (i < PDIM) bias[i] = W1b[i] + W2b[i];
    if (i < N_SAMPLES) seg[i] = lbatch[i] * NL + label[i];
    if (i < NSEG) hist[i] = 0;
}

__global__ __launch_bounds__(256) void hist_kernel(
    const int* __restrict__ seg, int* __restrict__ hist)
{
    int i = blockIdx.x * 256 + threadIdx.x;
    atomicAdd(&hist[seg[i]], 1);
}

// ---------------------------------------------------------------------------
// scan: single WG exclusive prefix over hist[3200] -> offs[3201], cursor copy
// ---------------------------------------------------------------------------
#define SCAN_BPT 13   // 256*13 = 3328 >= 3200
__global__ __launch_bounds__(256) void scan_kernel(
    const int* __restrict__ hist, int* __restrict__ offs, int* __restrict__ cursor)
{
    __shared__ int ps[256];
    const int t = threadIdx.x;
    int local = 0;
    #pragma unroll
    for (int k = 0; k < SCAN_BPT; ++k) {
        int bin = t * SCAN_BPT + k;
        if (bin < NSEG) local += hist[bin];
    }
    ps[t] = local;
    __syncthreads();
    for (int d = 1; d < 256; d <<= 1) {
        int v = (t >= d) ? ps[t - d] : 0;
        __syncthreads();
        ps[t] += v;
        __syncthreads();
    }
    int run = ps[t] - local;   // exclusive start for this thread's range
    #pragma unroll
    for (int k = 0; k < SCAN_BPT; ++k) {
        int bin = t * SCAN_BPT + k;
        if (bin < NSEG) {
            offs[bin] = run;
            cursor[bin] = run;
            run += hist[bin];
        }
    }
    if (t == 255) offs[NSEG] = ps[255];   // = N_SAMPLES
}

__global__ __launch_bounds__(256) void scatter_kernel(
    const int* __restrict__ seg, int* __restrict__ cursor, int* __restrict__ perm)
{
    int i = blockIdx.x * 256 + threadIdx.x;
    int pos = atomicAdd(&cursor[seg[i]], 1);
    perm[pos] = i;
}

// ---------------------------------------------------------------------------
// segsum v4: wave = (segment, 256-col chunk), lane = float4. Rows batched
// 8-at-a-time into explicit registers so 8 independent 1KB wave-loads are in
// flight before any use (v3's VGPR=16 forced per-row vmcnt(0) serialization).
// ---------------------------------------------------------------------------
__global__ __launch_bounds__(256) void segsum_kernel(
    const float* __restrict__ x, const int* __restrict__ perm,
    const int* __restrict__ offs,
    unsigned short* __restrict__ xb, float* __restrict__ sum_bl)
{
    const int tid = threadIdx.x;
    const int w = tid >> 6, lane = tid & 63;
    const int s = blockIdx.y * 4 + w;              // segment, 0..3199
    const int c = blockIdx.x * 256 + lane * 4;     // column (float4 per lane)
    const int beg = offs[s], end = offs[s + 1];

    floatx4 sum = {0.f, 0.f, 0.f, 0.f};
    for (int base = beg; base < end; base += 64) {
        int p = (base + lane < end) ? perm[base + lane] : 0;
        const int n = min(end - base, 64);
        for (int j0 = 0; j0 < n; j0 += 8) {
            const int m = min(n - j0, 8);
            int rr[8];
            floatx4 v[8];
            #pragma unroll
            for (int j = 0; j < 8; ++j) {
                rr[j] = __shfl(p, min(j0 + j, n - 1));          // clamp: dup loads harmless
                v[j] = *(const floatx4*)&x[(size_t)rr[j] * DIM + c];
            }
            #pragma unroll
            for (int j = 0; j < 8; ++j) {
                if (j < m) {
                    sum += v[j];
                    ushort4 o;
                    o.x = f32_to_bf16(v[j][0]); o.y = f32_to_bf16(v[j][1]);
                    o.z = f32_to_bf16(v[j][2]); o.w = f32_to_bf16(v[j][3]);
                    *(ushort4*)&xb[(size_t)rr[j] * DIM + c] = o;
                }
            }
        }
    }
    *(floatx4*)&sum_bl[(size_t)s * DIM + c] = sum;
}

// ---------------------------------------------------------------------------
// sumb: sum_b[b][:] = sum over 100 labels of sum_bl[b*NL+l][:]
// ---------------------------------------------------------------------------
__global__ __launch_bounds__(256) void sumb_kernel(
    const float* __restrict__ sum_bl, float* __restrict__ sum_b)
{
    int idx = blockIdx.x * 256 + threadIdx.x;   // NB * DIM/4 total
    int b = idx / (DIM / 4);
    int c = (idx % (DIM / 4)) * 4;
    floatx4 t = {0.f, 0.f, 0.f, 0.f};
    #pragma unroll 4
    for (int l = 0; l < NL; ++l)
        t += *(const floatx4*)&sum_bl[(size_t)(b * NL + l) * DIM + c];
    *(floatx4*)&sum_b[(size_t)b * DIM + c] = t;
}

// ---------------------------------------------------------------------------
// meanm: fully parallel LOO mean -> Mb bf16. thread = (segment, 4 cols)
// ---------------------------------------------------------------------------
__global__ __launch_bounds__(256) void meanm_kernel(
    const float* __restrict__ sum_bl, const float* __restrict__ sum_b,
    const int* __restrict__ hist, const int* __restrict__ offs,
    unsigned short* __restrict__ Mb)
{
    int idx = blockIdx.x * 256 + threadIdx.x;  // NSEG * 512 total
    int s = idx >> 9;
    int c = (idx & 511) * 4;
    int b = s / NL;
    int cntb = offs[(b + 1) * NL] - offs[b * NL];
    int dc = cntb - hist[s];
    float inv = (dc > 0) ? 1.f / (float)dc : 0.f;
    floatx4 sl = *(const floatx4*)&sum_bl[(size_t)s * DIM + c];
    floatx4 sb = *(const floatx4*)&sum_b[(size_t)b * DIM + c];
    ushort4 o;
    o.x = f32_to_bf16((sb[0] - sl[0]) * inv);
    o.y = f32_to_bf16((sb[1] - sl[1]) * inv);
    o.z = f32_to_bf16((sb[2] - sl[2]) * inv);
    o.w = f32_to_bf16((sb[3] - sl[3]) * inv);
    *(ushort4*)&Mb[(size_t)s * DIM + c] = o;
}

// ---------------------------------------------------------------------------
// GEMM: C[M,256] = A[M,K]_bf16 @ B[256,K]_bf16^T  (m97 structure)
// FUSE epilogue: += bias[col] + add[seg[row]*256 + col]
// ---------------------------------------------------------------------------
template<int BM, int BN, bool FUSE>
__global__ __launch_bounds__(256) void gemm_bt_kernel(
    const unsigned short* __restrict__ A,
    const unsigned short* __restrict__ B,
    float* __restrict__ C,
    const float* __restrict__ bias,
    const float* __restrict__ add,
    const int* __restrict__ seg,
    int K)
{
    constexpr int HBM = BM / 2, HBN = BN / 2;
    constexpr int FM = BM / 32, FN = BN / 32;
    __shared__ __align__(16) unsigned short ldsA[BM * 32];
    __shared__ __align__(16) unsigned short ldsB[BN * 32];
    const int tid = threadIdx.x;
    const int lane = tid & 63;
    const int wave = tid >> 6;
    const int wr = wave >> 1, wc = wave & 1;
    const int quad = lane >> 4, l15 = lane & 15;
    const int m0 = blockIdx.x * BM;
    const int n0 = blockIdx.y * BN;
    const int srow = lane >> 2, schunk = lane & 3;

    floatx4 acc[FM][FN];
    #pragma unroll
    for (int i = 0; i < FM; ++i)
        #pragma unroll
        for (int j = 0; j < FN; ++j) acc[i][j] = (floatx4){0.f, 0.f, 0.f, 0.f};

    const unsigned short* Abase = A + (size_t)(m0 + srow) * K + schunk * 8;
    const unsigned short* Bbase = B + (size_t)(n0 + srow) * K + schunk * 8;

    for (int kk = 0; kk < K; kk += 32) {
        __syncthreads();
        #pragma unroll
        for (int ii = 0; ii < BM / 64; ++ii) {
            const int ch = ii * 4 + wave;
            __builtin_amdgcn_global_load_lds(
                (const __attribute__((address_space(1))) void*)(Abase + (size_t)ch * 16 * K + kk),
                (__attribute__((address_space(3))) void*)&ldsA[ch * 16 * 32], 16, 0, 0);
        }
        #pragma unroll
        for (int ii = 0; ii < BN / 64; ++ii) {
            const int ch = ii * 4 + wave;
            __builtin_amdgcn_global_load_lds(
                (const __attribute__((address_space(1))) void*)(Bbase + (size_t)ch * 16 * K + kk),
                (__attribute__((address_space(3))) void*)&ldsB[ch * 16 * 32], 16, 0, 0);
        }
        __syncthreads();

        bf16x8 af[FM], bfr[FN];
        #pragma unroll
        for (int mi = 0; mi < FM; ++mi)
            af[mi] = *(const bf16x8*)&ldsA[(wr * HBM + mi * 16 + l15) * 32 + quad * 8];
        #pragma unroll
        for (int ni = 0; ni < FN; ++ni)
            bfr[ni] = *(const bf16x8*)&ldsB[(wc * HBN + ni * 16 + l15) * 32 + quad * 8];
        #pragma unroll
        for (int mi = 0; mi < FM; ++mi)
            #pragma unroll
            for (int ni = 0; ni < FN; ++ni)
                acc[mi][ni] = __builtin_amdgcn_mfma_f32_16x16x32_bf16(
                    af[mi], bfr[ni], acc[mi][ni], 0, 0, 0);
    }

    #pragma unroll
    for (int mi = 0; mi < FM; ++mi) {
        const int rbase = m0 + wr * HBM + mi * 16 + quad * 4;
        #pragma unroll
        for (int ni = 0; ni < FN; ++ni) {
            const int col = n0 + wc * HBN + ni * 16 + l15;
            float bsum = 0.f;
            if constexpr (FUSE) bsum = bias[col];
            #pragma unroll
            for (int r = 0; r < 4; ++r) {
                const int row = rbase + r;
                float v = acc[mi][ni][r];
                if constexpr (FUSE) v += bsum + add[(size_t)seg[row] * PDIM + col];
                C[(size_t)row * PDIM + col] = v;
            }
        }
    }
}

// ---------------------------------------------------------------------------
extern "C" void kernel_launch(void* const* d_in, const int* in_sizes, int n_in,
                              void* d_out, int out_size, void* d_ws, size_t ws_size,
                              hipStream_t stream)
{
    const float* x      = (const float*)d_in[0];
    const int*   label  = (const int*)d_in[1];
    const int*   lbatch = (const int*)d_in[2];
    const float* W1w    = (const float*)d_in[3];
    const float* W1b    = (const float*)d_in[4];
    const float* W2w    = (const float*)d_in[5];
    const float* W2b    = (const float*)d_in[6];
    float* out = (float*)d_out;

    char* ws = (char*)d_ws;
    size_t off = 0;
    auto alloc = [&](size_t bytes) {
        void* p = ws + off;
        off = (off + bytes + 255) & ~(size_t)255;
        return p;
    };
    unsigned short* xb   = (unsigned short*)alloc((size_t)N_SAMPLES * DIM * 2); // 67 MB
    unsigned short* Mb   = (unsigned short*)alloc((size_t)NSEG * DIM * 2);      // 13 MB
    unsigned short* W1bf = (unsigned short*)alloc((size_t)PDIM * DIM * 2);
    unsigned short* W2bf = (unsigned short*)alloc((size_t)PDIM * DIM * 2);
    float* MW2    = (float*)alloc((size_t)NSEG * PDIM * 4);                     // 3.3 MB
    float* sum_bl = (float*)alloc((size_t)NSEG * DIM * 4);                      // 26 MB
    float* sum_b  = (float*)alloc((size_t)NB * DIM * 4);
    float* bias   = (float*)alloc(PDIM * 4);
    int*   seg    = (int*)alloc(N_SAMPLES * 4);
    int*   perm   = (int*)alloc(N_SAMPLES * 4);
    int*   hist   = (int*)alloc(NSEG * 4);
    int*   offs   = (int*)alloc((NSEG + 1) * 4);
    int*   cursor = (int*)alloc(NSEG * 4);

    prep_kernel<<<PDIM * DIM / 256, 256, 0, stream>>>(
        W1w, W1b, W2w, W2b, label, lbatch, W1bf, W2bf, bias, seg, hist);

    hist_kernel<<<N_SAMPLES / 256, 256, 0, stream>>>(seg, hist);
    scan_kernel<<<1, 256, 0, stream>>>(hist, offs, cursor);
    scatter_kernel<<<N_SAMPLES / 256, 256, 0, stream>>>(seg, cursor, perm);

    segsum_kernel<<<dim3(DIM / 256, NSEG / 4), 256, 0, stream>>>(
        x, perm, offs, xb, sum_bl);

    sumb_kernel<<<NB * (DIM / 4) / 256, 256, 0, stream>>>(sum_bl, sum_b);

    meanm_kernel<<<NSEG * 512 / 256, 256, 0, stream>>>(sum_bl, sum_b, hist, offs, Mb);

    // MW2[3200,256] = M @ W2^T
    gemm_bt_kernel<64, 64, false><<<dim3(NSEG / 64, PDIM / 64), 256, 0, stream>>>(
        Mb, W2bf, MW2, nullptr, nullptr, nullptr, DIM);

    // out[16384,256] = x @ W1^T + bias + MW2[seg]  (m97 128x128 shape)
    gemm_bt_kernel<128, 128, true><<<dim3(N_SAMPLES / 128, PDIM / 128), 256, 0, stream>>>(
        xb, W1bf, out, bias, MW2, seg, DIM);
}